// Round 2
// baseline (234.562 us; speedup 1.0000x reference)
//
#include <hip/hip_runtime.h>
#include <hip/hip_bf16.h>

typedef __attribute__((ext_vector_type(8))) short short8;
typedef __attribute__((ext_vector_type(4))) float f32x4;

#define CIN   16
#define COUT  64
#define HH    256
#define WW    256
#define OHH   254
#define OWW   254

// LDS patch layout: [18 h][18 w][24 ushort]  (16 ci used + 8 pad for bank spread)
#define WSTRIDE   24
#define ROWSTRIDE (18 * WSTRIDE)   // 432 ushorts per h row

__device__ __forceinline__ ushort f2bf(float f) {
    unsigned u = __builtin_bit_cast(unsigned, f);
    unsigned r = (u + 0x7fffu + ((u >> 16) & 1u)) >> 16;
    return (ushort)r;
}

// min-reduce over the 16-lane group via DPP: xor1, xor2 (quad_perm),
// then group-wise xor4 (row_half_mirror) and xor8 (row_mirror).
// Result replicated in all 16 lanes. Pure VALU, no LDS round-trip.
__device__ __forceinline__ float dpp_min16(float v) {
    int i;
    i = __builtin_bit_cast(int, v);
    v = fminf(v, __builtin_bit_cast(float, __builtin_amdgcn_mov_dpp(i, 0xB1, 0xF, 0xF, false)));
    i = __builtin_bit_cast(int, v);
    v = fminf(v, __builtin_bit_cast(float, __builtin_amdgcn_mov_dpp(i, 0x4E, 0xF, 0xF, false)));
    i = __builtin_bit_cast(int, v);
    v = fminf(v, __builtin_bit_cast(float, __builtin_amdgcn_mov_dpp(i, 0x141, 0xF, 0xF, false)));
    i = __builtin_bit_cast(int, v);
    v = fminf(v, __builtin_bit_cast(float, __builtin_amdgcn_mov_dpp(i, 0x140, 0xF, 0xF, false)));
    return v;
}

// fast tanh(tanh(x)): exp2-based, ~1e-6 rel err, clamp avoids inf/inf
__device__ __forceinline__ float dtanh2(float x) {
    const float K = 2.8853900817779268f;   // 2*log2(e)
    float xc = fminf(fmaxf(x, -9.0f), 9.0f);
    float e1 = __builtin_amdgcn_exp2f(K * xc);
    float t1 = 1.0f - 2.0f * __builtin_amdgcn_rcpf(e1 + 1.0f);
    float e2 = __builtin_amdgcn_exp2f(K * t1);
    return 1.0f - 2.0f * __builtin_amdgcn_rcpf(e2 + 1.0f);
}

// Rearrange conv weights (fp32 OIHW [64][16][3][3]) into per-lane bf16 B-fragments:
// wfrag[p][j][lane][r]: k_local = 8*(lane>>4)+r, tap = 2p + (k_local>=16), ci = k_local&15,
// co = 16j + (lane&15). tap==9 (pair 4 upper half) -> 0 so garbage A contributes nothing.
__global__ void prep_weights(const float* __restrict__ wsrc, ushort* __restrict__ wfrag) {
    int idx = blockIdx.x * 256 + threadIdx.x;
    if (idx >= 10240) return;
    int r    = idx & 7;
    int lane = (idx >> 3) & 63;
    int j    = (idx >> 9) & 3;
    int p    = idx >> 11;
    int kl   = ((lane >> 4) << 3) + r;
    int tap  = 2 * p + (kl >> 4);
    int ci   = kl & 15;
    int co   = j * 16 + (lane & 15);
    float v = 0.0f;
    if (tap <= 8) {
        int kh = tap / 3, kw = tap - 3 * (tap / 3);
        v = wsrc[(co * CIN + ci) * 9 + kh * 3 + kw];
    }
    wfrag[idx] = f2bf(v);
}

__global__ __launch_bounds__(256, 4) void conv_min_tanh(
        const float* __restrict__ x, const ushort* __restrict__ wfrag,
        const float* __restrict__ bias, float* __restrict__ out) {
    __shared__ ushort lds[18 * ROWSTRIDE];   // 15552 B

    const int tid = threadIdx.x;
    const int n   = blockIdx.z;
    const int oh0 = blockIdx.y * 16;
    const int ow0 = blockIdx.x * 16;

    // ---- stage input patch (18 x 18 x 16ci) NCHW fp32 -> LDS [h][w][ci] bf16 ----
    const float* xb = x + (size_t)n * CIN * HH * WW;
    for (int it = 0; it < 6; ++it) {
        int idx = tid + it * 256;
        if (idx < 1296) {                       // 18 w * (18 h * 4 cgroups)
            int wp   = idx % 18;
            int rest = idx / 18;
            int cg   = rest & 3;                // ci group of 4
            int hp   = rest >> 2;
            int hg = min(oh0 + hp, HH - 1);     // clamp edges (garbage rows never stored)
            int wg = min(ow0 + wp, WW - 1);
            const float* src = xb + (size_t)(cg * 4) * (HH * WW) + hg * WW + wg;
            float f0 = src[0];
            float f1 = src[HH * WW];
            float f2 = src[2 * HH * WW];
            float f3 = src[3 * HH * WW];
            unsigned p0, p1;
            asm("v_cvt_pk_bf16_f32 %0, %1, %2" : "=v"(p0) : "v"(f0), "v"(f1));
            asm("v_cvt_pk_bf16_f32 %0, %1, %2" : "=v"(p1) : "v"(f2), "v"(f3));
            uint2 pk; pk.x = p0; pk.y = p1;
            *reinterpret_cast<uint2*>(&lds[hp * ROWSTRIDE + wp * WSTRIDE + cg * 4]) = pk;
        }
    }

    const int lane = tid & 63;
    const int wid  = tid >> 6;
    const int g    = lane >> 4;
    const int mm   = lane & 15;

    // ---- B fragments (weights) -> registers, reused across this wave's 4 M-tiles ----
    short8 wf[5][4];
#pragma unroll
    for (int p = 0; p < 5; ++p)
#pragma unroll
        for (int j = 0; j < 4; ++j)
            wf[p][j] = *reinterpret_cast<const short8*>(wfrag + (((p * 4 + j) * 64 + lane) * 8));

    float bj[4];
#pragma unroll
    for (int j = 0; j < 4; ++j) bj[j] = bias[j * 16 + mm];

    // per-pair LDS offset (ushorts), excluding the ohl*ROWSTRIDE term
    int aoff[5];
#pragma unroll
    for (int p = 0; p < 5; ++p) {
        int tap = 2 * p + (g >> 1);
        if (tap > 8) tap = 8;                 // pair-4 upper half: B is zero, read anything valid
        int kh = tap / 3, kw = tap - 3 * (tap / 3);
        aoff[p] = kh * ROWSTRIDE + (mm + kw) * WSTRIDE + (g & 1) * 8;
    }

    // bpermute byte-index: dest lane (g,mm) pulls row mm's min, which lives in
    // group mm>>2's lanes as their v[mm&3]; source lane = (mm>>2)*16 + (mm&3)
    const int s4 = ((((mm >> 2) << 4) | (mm & 3)) << 2);

    __syncthreads();

    float res = 0.0f;

    // ---- each wave: 4 M-tiles (one oh row of 16 ow each) ----
#pragma unroll
    for (int t = 0; t < 4; ++t) {
        const int ohl = wid * 4 + t;
        f32x4 acc0 = {bj[0], bj[0], bj[0], bj[0]};   // bias folded into C-init
        f32x4 acc1 = {bj[1], bj[1], bj[1], bj[1]};
        f32x4 acc2 = {bj[2], bj[2], bj[2], bj[2]};
        f32x4 acc3 = {bj[3], bj[3], bj[3], bj[3]};
        const int base = ohl * ROWSTRIDE;
#pragma unroll
        for (int p = 0; p < 5; ++p) {
            short8 a = *reinterpret_cast<const short8*>(&lds[base + aoff[p]]);
            acc0 = __builtin_amdgcn_mfma_f32_16x16x32_bf16(a, wf[p][0], acc0, 0, 0, 0);
            acc1 = __builtin_amdgcn_mfma_f32_16x16x32_bf16(a, wf[p][1], acc1, 0, 0, 0);
            acc2 = __builtin_amdgcn_mfma_f32_16x16x32_bf16(a, wf[p][2], acc2, 0, 0, 0);
            acc3 = __builtin_amdgcn_mfma_f32_16x16x32_bf16(a, wf[p][3], acc3, 0, 0, 0);
        }

        // min over the 4 channel tiles, then over the 16 columns (channels)
        float v[4];
#pragma unroll
        for (int r = 0; r < 4; ++r) {
            v[r] = fminf(fminf(acc0[r], acc1[r]), fminf(acc2[r], acc3[r]));
            v[r] = dpp_min16(v[r]);           // row-min replicated across 16 lanes
        }

        // compact: this wave-tile's 16 row-mins -> the 16 lanes with g==t
        float a01  = (mm & 1) ? v[1] : v[0];
        float a23  = (mm & 1) ? v[3] : v[2];
        float vsel = (mm & 2) ? a23 : a01;    // = v[mm&3] without dynamic indexing
        float got  = __builtin_bit_cast(float,
                        __builtin_amdgcn_ds_bpermute(s4, __builtin_bit_cast(int, vsel)));
        res = (g == t) ? got : res;
    }

    // one fast double-tanh + one coalesced store per lane (64 outputs/wave)
    float y = dtanh2(res);
    const int oh = oh0 + wid * 4 + g;
    const int ow = ow0 + mm;
    if (oh < OHH && ow < OWW)
        out[((size_t)n * OHH + oh) * OWW + ow] = y;
}

extern "C" void kernel_launch(void* const* d_in, const int* in_sizes, int n_in,
                              void* d_out, int out_size, void* d_ws, size_t ws_size,
                              hipStream_t stream) {
    const float* x = (const float*)d_in[0];
    const float* w = (const float*)d_in[1];
    const float* b = (const float*)d_in[2];
    float* out     = (float*)d_out;
    ushort* wfrag  = (ushort*)d_ws;          // 20 KiB

    prep_weights<<<40, 256, 0, stream>>>(w, wfrag);
    dim3 grid(16, 16, 32);                   // (owT, ohT, n)
    conv_min_tanh<<<grid, dim3(256, 1, 1), 0, stream>>>(x, wfrag, b, out);
}

// Round 3
// 83.535 us; speedup vs baseline: 2.8080x; 2.8080x over previous
//
#include <hip/hip_runtime.h>
#include <hip/hip_bf16.h>

typedef __attribute__((ext_vector_type(8))) short short8;
typedef __attribute__((ext_vector_type(4))) float f32x4;

#define CIN   16
#define COUT  64
#define HH    256
#define WW    256
#define OHH   254
#define OWW   254

// LDS patch layout: [18 h][18 w][24 ushort]  (16 ci used + 8 pad -> 48B w-stride,
// 2-way bank alias only, which is free)
#define WSTRIDE   24
#define ROWSTRIDE (18 * WSTRIDE)   // 432 ushorts per h row

__device__ __forceinline__ ushort f2bf(float f) {
    unsigned u = __builtin_bit_cast(unsigned, f);
    unsigned r = (u + 0x7fffu + ((u >> 16) & 1u)) >> 16;
    return (ushort)r;
}

// min-reduce over each 16-lane group via DPP (xor1, xor2, mirror7, mirror15).
// Result replicated in all 16 lanes of the group. Pure VALU, no LDS.
__device__ __forceinline__ float dpp_min16(float v) {
    int i;
    i = __builtin_bit_cast(int, v);
    v = fminf(v, __builtin_bit_cast(float, __builtin_amdgcn_mov_dpp(i, 0xB1, 0xF, 0xF, false)));
    i = __builtin_bit_cast(int, v);
    v = fminf(v, __builtin_bit_cast(float, __builtin_amdgcn_mov_dpp(i, 0x4E, 0xF, 0xF, false)));
    i = __builtin_bit_cast(int, v);
    v = fminf(v, __builtin_bit_cast(float, __builtin_amdgcn_mov_dpp(i, 0x141, 0xF, 0xF, false)));
    i = __builtin_bit_cast(int, v);
    v = fminf(v, __builtin_bit_cast(float, __builtin_amdgcn_mov_dpp(i, 0x140, 0xF, 0xF, false)));
    return v;
}

// fast tanh(tanh(x)): exp2-based (verified absmax 3.9e-3 in R1/R2)
__device__ __forceinline__ float dtanh2(float x) {
    const float K = 2.8853900817779268f;   // 2*log2(e)
    float xc = fminf(fmaxf(x, -9.0f), 9.0f);
    float e1 = __builtin_amdgcn_exp2f(K * xc);
    float t1 = 1.0f - 2.0f * __builtin_amdgcn_rcpf(e1 + 1.0f);
    float e2 = __builtin_amdgcn_exp2f(K * t1);
    return 1.0f - 2.0f * __builtin_amdgcn_rcpf(e2 + 1.0f);
}

// Rearrange conv weights (fp32 OIHW [64][16][3][3]) into per-lane bf16 B-fragments:
// wfrag[p][j][lane][r]: k_local = 8*(lane>>4)+r, tap = 2p + (k_local>=16), ci = k_local&15,
// co = 16j + (lane&15). tap==9 (pair 4 upper half) -> 0 so garbage A contributes nothing.
__global__ void prep_weights(const float* __restrict__ wsrc, ushort* __restrict__ wfrag) {
    int idx = blockIdx.x * 256 + threadIdx.x;
    if (idx >= 10240) return;
    int r    = idx & 7;
    int lane = (idx >> 3) & 63;
    int j    = (idx >> 9) & 3;
    int p    = idx >> 11;
    int kl   = ((lane >> 4) << 3) + r;
    int tap  = 2 * p + (kl >> 4);
    int ci   = kl & 15;
    int co   = j * 16 + (lane & 15);
    float v = 0.0f;
    if (tap <= 8) {
        int kh = tap / 3, kw = tap - 3 * (tap / 3);
        v = wsrc[(co * CIN + ci) * 9 + kh * 3 + kw];
    }
    wfrag[idx] = f2bf(v);
}

__global__ __launch_bounds__(256, 4) void conv_min_tanh(
        const float* __restrict__ x, const ushort* __restrict__ wfrag,
        const float* __restrict__ bias, float* __restrict__ out) {
    __shared__ ushort lds[18 * ROWSTRIDE];               // 15552 B
    __shared__ __align__(16) float red[2][16][16];       // 2 KiB partial-min planes

    const int tid = threadIdx.x;
    const int n   = blockIdx.z;
    const int oh0 = blockIdx.y * 16;
    const int ow0 = blockIdx.x * 16;

    // ---- stage input patch (18 x 18 x 16ci) NCHW fp32 -> LDS [h][w][ci] bf16 ----
    const float* xb = x + (size_t)n * CIN * HH * WW;
    for (int it = 0; it < 6; ++it) {
        int idx = tid + it * 256;
        if (idx < 1296) {                       // 18 w * (18 h * 4 cgroups)
            int wp   = idx % 18;
            int rest = idx / 18;
            int cg   = rest & 3;                // ci group of 4
            int hp   = rest >> 2;
            int hg = min(oh0 + hp, HH - 1);     // clamp edges (garbage rows never stored)
            int wg = min(ow0 + wp, WW - 1);
            const float* src = xb + (size_t)(cg * 4) * (HH * WW) + hg * WW + wg;
            float f0 = src[0];
            float f1 = src[HH * WW];
            float f2 = src[2 * HH * WW];
            float f3 = src[3 * HH * WW];
            unsigned p0, p1;
            asm("v_cvt_pk_bf16_f32 %0, %1, %2" : "=v"(p0) : "v"(f0), "v"(f1));
            asm("v_cvt_pk_bf16_f32 %0, %1, %2" : "=v"(p1) : "v"(f2), "v"(f3));
            uint2 pk; pk.x = p0; pk.y = p1;
            *reinterpret_cast<uint2*>(&lds[hp * ROWSTRIDE + wp * WSTRIDE + cg * 4]) = pk;
        }
    }

    const int lane = tid & 63;
    const int wid  = tid >> 6;
    const int g    = lane >> 4;
    const int mm   = lane & 15;
    const int jp   = wid & 1;      // channel pair: j = 2*jp, 2*jp+1
    const int rh   = wid >> 1;     // row half: rows rh*8 .. rh*8+7

    // ---- this wave's 2 B-tiles (weights) -> registers (40 VGPRs) ----
    short8 wf0[5], wf1[5];
#pragma unroll
    for (int p = 0; p < 5; ++p) {
        wf0[p] = *reinterpret_cast<const short8*>(wfrag + (((p * 4 + 2 * jp)     * 64 + lane) * 8));
        wf1[p] = *reinterpret_cast<const short8*>(wfrag + (((p * 4 + 2 * jp + 1) * 64 + lane) * 8));
    }
    const float b0 = bias[(2 * jp)     * 16 + mm];
    const float b1 = bias[(2 * jp + 1) * 16 + mm];

    // per-pair LDS offset (ushorts), excluding the row*ROWSTRIDE term
    int aoff[5];
#pragma unroll
    for (int p = 0; p < 5; ++p) {
        int tap = 2 * p + (g >> 1);
        if (tap > 8) tap = 8;                 // pair-4 upper half: B is zero, read anything valid
        int kh = tap / 3, kw = tap - 3 * (tap / 3);
        aoff[p] = kh * ROWSTRIDE + (mm + kw) * WSTRIDE + (g & 1) * 8;
    }

    __syncthreads();

    // ---- 8 rows per wave; per row: 5 A-reads, 10 MFMAs (2 channel tiles) ----
#pragma unroll 2
    for (int i = 0; i < 8; ++i) {
        const int row  = rh * 8 + i;
        const int base = row * ROWSTRIDE;
        short8 a[5];
#pragma unroll
        for (int p = 0; p < 5; ++p)
            a[p] = *reinterpret_cast<const short8*>(&lds[base + aoff[p]]);
        f32x4 acc0 = {b0, b0, b0, b0};        // bias folded into C-init
        f32x4 acc1 = {b1, b1, b1, b1};
#pragma unroll
        for (int p = 0; p < 5; ++p) {
            acc0 = __builtin_amdgcn_mfma_f32_16x16x32_bf16(a[p], wf0[p], acc0, 0, 0, 0);
            acc1 = __builtin_amdgcn_mfma_f32_16x16x32_bf16(a[p], wf1[p], acc1, 0, 0, 0);
        }
        // channel-min: first the 2 register tiles, then the 16 lanes (channels) per group
        f32x4 vv;
#pragma unroll
        for (int r = 0; r < 4; ++r)
            vv[r] = dpp_min16(fminf(acc0[r], acc1[r]));
        if (mm == 0)                           // one f32x4 per 16-lane group
            *reinterpret_cast<f32x4*>(&red[jp][row][g * 4]) = vv;
    }

    __syncthreads();

    // ---- final: min across the 2 channel-pair planes, double-tanh, store ----
    const int ohl = tid >> 4, owl = tid & 15;
    const float m = fminf(red[0][ohl][owl], red[1][ohl][owl]);
    const float y = dtanh2(m);
    const int oh = oh0 + ohl, ow = ow0 + owl;
    if (oh < OHH && ow < OWW)
        out[((size_t)n * OHH + oh) * OWW + ow] = y;
}

extern "C" void kernel_launch(void* const* d_in, const int* in_sizes, int n_in,
                              void* d_out, int out_size, void* d_ws, size_t ws_size,
                              hipStream_t stream) {
    const float* x = (const float*)d_in[0];
    const float* w = (const float*)d_in[1];
    const float* b = (const float*)d_in[2];
    float* out     = (float*)d_out;
    ushort* wfrag  = (ushort*)d_ws;          // 20 KiB

    prep_weights<<<40, 256, 0, stream>>>(w, wfrag);
    dim3 grid(16, 16, 32);                   // (owT, ohT, n)
    conv_min_tanh<<<grid, dim3(256, 1, 1), 0, stream>>>(x, wfrag, b, out);
}

// Round 4
// 75.596 us; speedup vs baseline: 3.1029x; 1.1050x over previous
//
#include <hip/hip_runtime.h>
#include <hip/hip_bf16.h>

typedef __attribute__((ext_vector_type(8))) short short8;
typedef __attribute__((ext_vector_type(4))) float f32x4;

#define CIN   16
#define COUT  64
#define HH    256
#define WW    256
#define OHH   254
#define OWW   254

// LDS patch layout: [18 h][18 w][24 ushort] (16 ci + 8 pad -> 48B w-stride)
#define WSTRIDE   24
#define ROWSTRIDE (18 * WSTRIDE)   // 432 ushorts per h row

__device__ __forceinline__ ushort f2bf(float f) {
    unsigned u = __builtin_bit_cast(unsigned, f);
    unsigned r = (u + 0x7fffu + ((u >> 16) & 1u)) >> 16;
    return (ushort)r;
}

// fast tanh(tanh(x)): exp2-based (verified absmax 3.9e-3 in R1-R3)
__device__ __forceinline__ float dtanh2(float x) {
    const float K = 2.8853900817779268f;   // 2*log2(e)
    float xc = fminf(fmaxf(x, -9.0f), 9.0f);
    float e1 = __builtin_amdgcn_exp2f(K * xc);
    float t1 = 1.0f - 2.0f * __builtin_amdgcn_rcpf(e1 + 1.0f);
    float e2 = __builtin_amdgcn_exp2f(K * t1);
    return 1.0f - 2.0f * __builtin_amdgcn_rcpf(e2 + 1.0f);
}

// Weights fp32 OIHW [64][16][3][3] -> per-lane bf16 fragments (now the A-operand):
// wfrag[p][j][lane][r]: k_local = 8*(lane>>4)+r, tap = 2p + (k_local>=16), ci = k_local&15,
// channel = 16j + (lane&15)  (A row = lane&15). tap==9 -> 0.
__global__ void prep_weights(const float* __restrict__ wsrc, ushort* __restrict__ wfrag) {
    int idx = blockIdx.x * 256 + threadIdx.x;
    if (idx >= 10240) return;
    int r    = idx & 7;
    int lane = (idx >> 3) & 63;
    int j    = (idx >> 9) & 3;
    int p    = idx >> 11;
    int kl   = ((lane >> 4) << 3) + r;
    int tap  = 2 * p + (kl >> 4);
    int ci   = kl & 15;
    int co   = j * 16 + (lane & 15);
    float v = 0.0f;
    if (tap <= 8) {
        int kh = tap / 3, kw = tap - 3 * (tap / 3);
        v = wsrc[(co * CIN + ci) * 9 + kh * 3 + kw];
    }
    wfrag[idx] = f2bf(v);
}

__global__ __launch_bounds__(256, 5) void conv_min_tanh(
        const float* __restrict__ x, const ushort* __restrict__ wfrag,
        const float* __restrict__ bias, float* __restrict__ out) {
    __shared__ ushort lds[18 * ROWSTRIDE];               // 15552 B
    __shared__ float red[2][4][16][17];                  // 8704 B partial-min planes

    const int tid = threadIdx.x;
    const int n   = blockIdx.z;
    const int oh0 = blockIdx.y * 16;
    const int ow0 = blockIdx.x * 16;

    // ---- stage input patch: each cell = one (h,w) position, all 16 ci ----
    const float* xb = x + (size_t)n * CIN * HH * WW;
    {
        auto stage_cell = [&](int c) {
            int hp = c / 18;
            int wp = c - hp * 18;
            int hg = min(oh0 + hp, HH - 1);       // clamped edge reads: garbage outputs discarded
            int wg = min(ow0 + wp, WW - 1);
            const float* src = xb + hg * WW + wg;
            float f[16];
#pragma unroll
            for (int ci = 0; ci < 16; ++ci) f[ci] = src[(size_t)ci * (HH * WW)];
            unsigned pk[8];
#pragma unroll
            for (int q = 0; q < 8; ++q)
                asm("v_cvt_pk_bf16_f32 %0, %1, %2" : "=v"(pk[q]) : "v"(f[2 * q]), "v"(f[2 * q + 1]));
            ushort* dst = &lds[hp * ROWSTRIDE + wp * WSTRIDE];
            *reinterpret_cast<uint4*>(dst)     = make_uint4(pk[0], pk[1], pk[2], pk[3]);
            *reinterpret_cast<uint4*>(dst + 8) = make_uint4(pk[4], pk[5], pk[6], pk[7]);
        };
        stage_cell(tid);
        if (tid < 324 - 256) stage_cell(tid + 256);
    }

    const int lane = tid & 63;
    const int wid  = tid >> 6;
    const int g    = lane >> 4;
    const int mm   = lane & 15;
    const int jp   = wid & 1;      // channel-tile pair: j = 2jp, 2jp+1
    const int rh   = wid >> 1;     // row half: rows rh*8 .. rh*8+7

    // ---- this wave's 2 weight tiles (A-operand) -> registers (40 VGPRs) ----
    short8 wf0[5], wf1[5];
#pragma unroll
    for (int p = 0; p < 5; ++p) {
        wf0[p] = *reinterpret_cast<const short8*>(wfrag + (((p * 4 + 2 * jp)     * 64 + lane) * 8));
        wf1[p] = *reinterpret_cast<const short8*>(wfrag + (((p * 4 + 2 * jp + 1) * 64 + lane) * 8));
    }
    // bias folded into acc init: D row = channel = 4g+r -> one float4 per tile
    const f32x4 binit0 = *reinterpret_cast<const f32x4*>(bias + (2 * jp) * 16 + 4 * g);
    const f32x4 binit1 = *reinterpret_cast<const f32x4*>(bias + (2 * jp + 1) * 16 + 4 * g);

    // per-pair pixel-fragment (B-operand) base pointers; row term folded as imm offsets
    const ushort* ap[5];
#pragma unroll
    for (int p = 0; p < 5; ++p) {
        int tap = 2 * p + (g >> 1);
        if (tap > 8) tap = 8;                 // pair-4 upper half: weights are zero there
        int kh = tap / 3, kw = tap - 3 * (tap / 3);
        ap[p] = &lds[(rh * 8 + kh) * ROWSTRIDE + (mm + kw) * WSTRIDE + (g & 1) * 8];
    }

    __syncthreads();

    // ---- 8 rows per wave; per row: 5 B-reads (imm offsets), 10 MFMAs, 8-instr epilogue ----
#pragma unroll
    for (int i = 0; i < 8; ++i) {
        f32x4 acc0 = binit0;
        f32x4 acc1 = binit1;
#pragma unroll
        for (int p = 0; p < 5; ++p) {
            short8 b = *reinterpret_cast<const short8*>(ap[p] + i * ROWSTRIDE);
            acc0 = __builtin_amdgcn_mfma_f32_16x16x32_bf16(wf0[p], b, acc0, 0, 0, 0);
            acc1 = __builtin_amdgcn_mfma_f32_16x16x32_bf16(wf1[p], b, acc1, 0, 0, 0);
        }
        // min over this lane's 8 channels (2 tiles x 4 acc rows); pixel = mm
        float v = fminf(fminf(fminf(acc0[0], acc0[1]), fminf(acc0[2], acc0[3])),
                        fminf(fminf(acc1[0], acc1[1]), fminf(acc1[2], acc1[3])));
        red[jp][g][rh * 8 + i][mm] = v;
    }

    __syncthreads();

    // ---- final: min across 8 partial planes, double-tanh, coalesced store ----
    const int ohl = tid >> 4, owl = tid & 15;
    float m = red[0][0][ohl][owl];
    m = fminf(m, red[0][1][ohl][owl]);
    m = fminf(m, red[0][2][ohl][owl]);
    m = fminf(m, red[0][3][ohl][owl]);
    m = fminf(m, red[1][0][ohl][owl]);
    m = fminf(m, red[1][1][ohl][owl]);
    m = fminf(m, red[1][2][ohl][owl]);
    m = fminf(m, red[1][3][ohl][owl]);
    const float y = dtanh2(m);
    const int oh = oh0 + ohl, ow = ow0 + owl;
    if (oh < OHH && ow < OWW)
        out[((size_t)n * OHH + oh) * OWW + ow] = y;
}

extern "C" void kernel_launch(void* const* d_in, const int* in_sizes, int n_in,
                              void* d_out, int out_size, void* d_ws, size_t ws_size,
                              hipStream_t stream) {
    const float* x = (const float*)d_in[0];
    const float* w = (const float*)d_in[1];
    const float* b = (const float*)d_in[2];
    float* out     = (float*)d_out;
    ushort* wfrag  = (ushort*)d_ws;          // 20 KiB

    prep_weights<<<40, 256, 0, stream>>>(w, wfrag);
    dim3 grid(16, 16, 32);                   // (owT, ohT, n)
    conv_min_tanh<<<grid, dim3(256, 1, 1), 0, stream>>>(x, wfrag, b, out);
}

// Round 5
// 62.924 us; speedup vs baseline: 3.7277x; 1.2014x over previous
//
#include <hip/hip_runtime.h>
#include <hip/hip_bf16.h>

typedef __attribute__((ext_vector_type(8))) short short8;
typedef __attribute__((ext_vector_type(4))) float f32x4;

#define CIN   16
#define COUT  64
#define HH    256
#define WW    256
#define OHH   254
#define OWW   254

// LDS patch: [2 cihalf][34 h][34 w][8 ci] bf16 -> 16B cells, fully aligned,
// w-stride 16B (2-way bank alias = free). Total 36,992 B.
#define CELLS   (34 * 34)          // 1156
#define HSTRIDE (34 * 8)           // ushorts per h row within one half

__device__ __forceinline__ ushort f2bf(float f) {
    unsigned u = __builtin_bit_cast(unsigned, f);
    unsigned r = (u + 0x7fffu + ((u >> 16) & 1u)) >> 16;
    return (ushort)r;
}

// fast tanh(tanh(x)): exp2-based (verified absmax 3.9e-3 in R1-R4)
__device__ __forceinline__ float dtanh2(float x) {
    const float K = 2.8853900817779268f;   // 2*log2(e)
    float xc = fminf(fmaxf(x, -9.0f), 9.0f);
    float e1 = __builtin_amdgcn_exp2f(K * xc);
    float t1 = 1.0f - 2.0f * __builtin_amdgcn_rcpf(e1 + 1.0f);
    float e2 = __builtin_amdgcn_exp2f(K * t1);
    return 1.0f - 2.0f * __builtin_amdgcn_rcpf(e2 + 1.0f);
}

// Weights fp32 OIHW [64][16][3][3] -> per-lane bf16 A-fragments:
// wfrag[p][j][lane][r]: k_local = 8*(lane>>4)+r, tap = 2p + (k_local>=16),
// ci = k_local&15, channel = 16j + (lane&15). tap==9 -> 0.
__global__ void prep_weights(const float* __restrict__ wsrc, ushort* __restrict__ wfrag) {
    int idx = blockIdx.x * 256 + threadIdx.x;
    if (idx >= 10240) return;
    int r    = idx & 7;
    int lane = (idx >> 3) & 63;
    int j    = (idx >> 9) & 3;
    int p    = idx >> 11;
    int kl   = ((lane >> 4) << 3) + r;
    int tap  = 2 * p + (kl >> 4);
    int ci   = kl & 15;
    int co   = j * 16 + (lane & 15);
    float v = 0.0f;
    if (tap <= 8) {
        int kh = tap / 3, kw = tap - 3 * (tap / 3);
        v = wsrc[(co * CIN + ci) * 9 + kh * 3 + kw];
    }
    wfrag[idx] = f2bf(v);
}

__global__ __launch_bounds__(256, 3) void conv_min_tanh(
        const float* __restrict__ x, const ushort* __restrict__ wfrag,
        const float* __restrict__ bias, float* __restrict__ out) {
    __shared__ ushort lds[2 * CELLS * 8];    // 36,992 B

    const int tid = threadIdx.x;
    const int n   = blockIdx.z;
    const int oh0 = blockIdx.y * 32;
    const int ow0 = blockIdx.x * 32;

    // ---- stage 34x34x16ci patch, NCHW fp32 -> bf16, cihalf-blocked ----
    const float* xb = x + (size_t)n * CIN * HH * WW;
    {
        auto stage_cell = [&](int c) {
            int hp = c / 34;
            int wp = c - hp * 34;
            int hg = min(oh0 + hp, HH - 1);   // clamped edge reads; outputs masked later
            int wg = min(ow0 + wp, WW - 1);
            const float* src = xb + hg * WW + wg;
            float f[16];
#pragma unroll
            for (int ci = 0; ci < 16; ++ci) f[ci] = src[(size_t)ci * (HH * WW)];
            unsigned pk[8];
#pragma unroll
            for (int q = 0; q < 8; ++q)
                asm("v_cvt_pk_bf16_f32 %0, %1, %2" : "=v"(pk[q]) : "v"(f[2 * q]), "v"(f[2 * q + 1]));
            ushort* d0 = &lds[(hp * 34 + wp) * 8];
            *reinterpret_cast<uint4*>(d0)             = make_uint4(pk[0], pk[1], pk[2], pk[3]);
            *reinterpret_cast<uint4*>(d0 + CELLS * 8) = make_uint4(pk[4], pk[5], pk[6], pk[7]);
        };
#pragma unroll
        for (int it = 0; it < 4; ++it) stage_cell(tid + it * 256);
        if (tid < CELLS - 1024) stage_cell(tid + 1024);
    }

    const int lane = tid & 63;
    const int wid  = tid >> 6;
    const int g    = lane >> 4;
    const int mm   = lane & 15;

    // ---- all 4 weight tiles (A-operand) -> registers (80 VGPRs) ----
    short8 wf0[5], wf1[5], wf2[5], wf3[5];
#pragma unroll
    for (int p = 0; p < 5; ++p) {
        wf0[p] = *reinterpret_cast<const short8*>(wfrag + (((p * 4 + 0) * 64 + lane) * 8));
        wf1[p] = *reinterpret_cast<const short8*>(wfrag + (((p * 4 + 1) * 64 + lane) * 8));
        wf2[p] = *reinterpret_cast<const short8*>(wfrag + (((p * 4 + 2) * 64 + lane) * 8));
        wf3[p] = *reinterpret_cast<const short8*>(wfrag + (((p * 4 + 3) * 64 + lane) * 8));
    }
    // bias into acc init: D row = channel-in-tile = 4g+r
    const f32x4 bi0 = *reinterpret_cast<const f32x4*>(bias +  0 + 4 * g);
    const f32x4 bi1 = *reinterpret_cast<const f32x4*>(bias + 16 + 4 * g);
    const f32x4 bi2 = *reinterpret_cast<const f32x4*>(bias + 32 + 4 * g);
    const f32x4 bi3 = *reinterpret_cast<const f32x4*>(bias + 48 + 4 * g);

    __syncthreads();

    // ---- each wave: rows wid*8..wid*8+7, 2 colhalves; 20 MFMA per pixel-group ----
#pragma unroll
    for (int ch = 0; ch < 2; ++ch) {
        // B-fragment base pointers for this colhalf (row term via imm offsets)
        const ushort* bp[5];
#pragma unroll
        for (int p = 0; p < 5; ++p) {
            int tap = 2 * p + (g >> 1);
            if (tap > 8) tap = 8;             // pair-4 upper half: weights are zero there
            int kh = tap / 3, kw = tap - 3 * (tap / 3);
            bp[p] = &lds[(g & 1) * (CELLS * 8) + (wid * 8 + kh) * HSTRIDE
                         + (ch * 16 + mm + kw) * 8];
        }
#pragma unroll
        for (int i = 0; i < 8; ++i) {
            f32x4 a0 = bi0, a1 = bi1, a2 = bi2, a3 = bi3;
#pragma unroll
            for (int p = 0; p < 5; ++p) {
                short8 b = *reinterpret_cast<const short8*>(bp[p] + i * HSTRIDE);
                a0 = __builtin_amdgcn_mfma_f32_16x16x32_bf16(wf0[p], b, a0, 0, 0, 0);
                a1 = __builtin_amdgcn_mfma_f32_16x16x32_bf16(wf1[p], b, a1, 0, 0, 0);
                a2 = __builtin_amdgcn_mfma_f32_16x16x32_bf16(wf2[p], b, a2, 0, 0, 0);
                a3 = __builtin_amdgcn_mfma_f32_16x16x32_bf16(wf3[p], b, a3, 0, 0, 0);
            }
            // in-lane min over 16 channels, then cross-group (xor16, xor32)
            float v = fminf(fminf(fminf(a0[0], a0[1]), fminf(a0[2], a0[3])),
                            fminf(fminf(a1[0], a1[1]), fminf(a1[2], a1[3])));
            v = fminf(v, fminf(fminf(fminf(a2[0], a2[1]), fminf(a2[2], a2[3])),
                               fminf(fminf(a3[0], a3[1]), fminf(a3[2], a3[3]))));
            v = fminf(v, __shfl_xor(v, 16, 64));
            v = fminf(v, __shfl_xor(v, 32, 64));
            const float y = dtanh2(v);
            const int oh = oh0 + wid * 8 + i;
            const int ow = ow0 + ch * 16 + mm;
            if (lane < 16 && oh < OHH && ow < OWW)
                out[((size_t)n * OHH + oh) * OWW + ow] = y;
        }
    }
}

extern "C" void kernel_launch(void* const* d_in, const int* in_sizes, int n_in,
                              void* d_out, int out_size, void* d_ws, size_t ws_size,
                              hipStream_t stream) {
    const float* x = (const float*)d_in[0];
    const float* w = (const float*)d_in[1];
    const float* b = (const float*)d_in[2];
    float* out     = (float*)d_out;
    ushort* wfrag  = (ushort*)d_ws;          // 20 KiB

    prep_weights<<<40, 256, 0, stream>>>(w, wfrag);
    dim3 grid(8, 8, 32);                     // (owT, ohT, n), 32x32 tiles
    conv_min_tanh<<<grid, dim3(256, 1, 1), 0, stream>>>(x, wfrag, b, out);
}